// Round 1
// baseline (202.518 us; speedup 1.0000x reference)
//
#include <hip/hip_runtime.h>
#include <math.h>

#define TPB 256

// R = I + a*K + b*K^2 with K=skew(v), K^2 = v v^T - th^2 I
// => R = (1 - b*th^2) I + b * v v^T + a * K   (matches reference incl. small-angle branch)
__device__ __forceinline__ void rodrigues(float v0, float v1, float v2, float R[9]) {
    float th2 = v0 * v0 + v1 * v1 + v2 * v2;
    float th  = sqrtf(th2);
    float s, c;
    sincosf(th, &s, &c);
    bool  sm = th < 1e-6f;
    float a  = sm ? 1.0f : s / th;
    float b  = sm ? 0.5f : (1.0f - c) / th2;
    float cc = 1.0f - b * th2;
    R[0] = cc + b * v0 * v0;      R[1] = b * v0 * v1 - a * v2;  R[2] = b * v0 * v2 + a * v1;
    R[3] = b * v0 * v1 + a * v2;  R[4] = cc + b * v1 * v1;      R[5] = b * v1 * v2 - a * v0;
    R[6] = b * v0 * v2 - a * v1;  R[7] = b * v1 * v2 + a * v0;  R[8] = cc + b * v2 * v2;
}

// One element: inputs (r,u,s,t) -> 3 float4 rows of [M | t].
// W/S/M association kept identical to the previously-verified kernel
// (S is symmetric: S10==S01 etc. are fp-identical, so only 6 entries computed).
__device__ __forceinline__ void affine_one(
    float r0, float r1, float r2,
    float u0, float u1, float u2,
    float s0, float s1, float s2,
    float t0, float t1, float t2,
    float4* __restrict__ o)
{
    float R[9], U[9];
    rodrigues(r0, r1, r2, R);
    rodrigues(u0, u1, u2, U);
    float d0 = expf(s0), d1 = expf(s1), d2 = expf(s2);

    // W = U * diag(d)
    float W0 = U[0]*d0, W1 = U[1]*d1, W2 = U[2]*d2;
    float W3 = U[3]*d0, W4 = U[4]*d1, W5 = U[5]*d2;
    float W6 = U[6]*d0, W7 = U[7]*d1, W8 = U[8]*d2;

    // S = W * U^T (symmetric)
    float S00 = W0*U[0] + W1*U[1] + W2*U[2];
    float S01 = W0*U[3] + W1*U[4] + W2*U[5];
    float S02 = W0*U[6] + W1*U[7] + W2*U[8];
    float S11 = W3*U[3] + W4*U[4] + W5*U[5];
    float S12 = W3*U[6] + W4*U[7] + W5*U[8];
    float S22 = W6*U[6] + W7*U[7] + W8*U[8];

    // M = R * S
    float M00 = R[0]*S00 + R[1]*S01 + R[2]*S02;
    float M01 = R[0]*S01 + R[1]*S11 + R[2]*S12;
    float M02 = R[0]*S02 + R[1]*S12 + R[2]*S22;
    float M10 = R[3]*S00 + R[4]*S01 + R[5]*S02;
    float M11 = R[3]*S01 + R[4]*S11 + R[5]*S12;
    float M12 = R[3]*S02 + R[4]*S12 + R[5]*S22;
    float M20 = R[6]*S00 + R[7]*S01 + R[8]*S02;
    float M21 = R[6]*S01 + R[7]*S11 + R[8]*S12;
    float M22 = R[6]*S02 + R[7]*S12 + R[8]*S22;

    o[0] = make_float4(M00, M01, M02, t0);
    o[1] = make_float4(M10, M11, M12, t1);
    o[2] = make_float4(M20, M21, M22, t2);
}

// 4 elements per thread: 4 elems x 3 floats = 12 floats = exactly 3 float4 per input
// array, and 12 float4 of output. No LDS, no barriers, no cross-thread exchange.
// 12 independent float4 loads issued up-front per thread for deep MLP.
__global__ __launch_bounds__(TPB, 4) void aff_kernel(
    const float4* __restrict__ trans,
    const float4* __restrict__ rotat,
    const float4* __restrict__ sdir,
    const float4* __restrict__ scal,
    float4* __restrict__ out,
    int B)
{
    const int nfull = B >> 2;                    // full 4-element groups
    const int g = blockIdx.x * TPB + threadIdx.x;

    if (g < nfull) {
        const int ib = 3 * g;
        // issue all 12 loads before any compute
        float4 ta = trans[ib], tb = trans[ib+1], tc = trans[ib+2];
        float4 ra = rotat[ib], rb = rotat[ib+1], rc = rotat[ib+2];
        float4 ua = sdir [ib], ub = sdir [ib+1], uc = sdir [ib+2];
        float4 sa = scal [ib], sb = scal [ib+1], sc = scal [ib+2];

        float4* o = out + 12 * g;
        // element 0: floats (a.x, a.y, a.z)
        affine_one(ra.x,ra.y,ra.z, ua.x,ua.y,ua.z, sa.x,sa.y,sa.z, ta.x,ta.y,ta.z, o);
        // element 1: floats (a.w, b.x, b.y)
        affine_one(ra.w,rb.x,rb.y, ua.w,ub.x,ub.y, sa.w,sb.x,sb.y, ta.w,tb.x,tb.y, o+3);
        // element 2: floats (b.z, b.w, c.x)
        affine_one(rb.z,rb.w,rc.x, ub.z,ub.w,uc.x, sb.z,sb.w,sc.x, tb.z,tb.w,tc.x, o+6);
        // element 3: floats (c.y, c.z, c.w)
        affine_one(rc.y,rc.z,rc.w, uc.y,uc.z,uc.w, sc.y,sc.z,sc.w, tc.y,tc.z,tc.w, o+9);
    } else if (g == nfull && (B & 3)) {
        // scalar tail (B % 4 != 0) — not hit for B = 2,000,000, kept for correctness
        const float* tf = (const float*)trans;
        const float* rf = (const float*)rotat;
        const float* uf = (const float*)sdir;
        const float* sf = (const float*)scal;
        for (int e = 4 * nfull; e < B; ++e) {
            affine_one(rf[3*e],rf[3*e+1],rf[3*e+2],
                       uf[3*e],uf[3*e+1],uf[3*e+2],
                       sf[3*e],sf[3*e+1],sf[3*e+2],
                       tf[3*e],tf[3*e+1],tf[3*e+2],
                       out + 3*e);
        }
    }
}

extern "C" void kernel_launch(void* const* d_in, const int* in_sizes, int n_in,
                              void* d_out, int out_size, void* d_ws, size_t ws_size,
                              hipStream_t stream) {
    int B = in_sizes[0] / 3;                     // 2,000,000 elements
    int groups = (B >> 2) + ((B & 3) ? 1 : 0);
    int blocks = (groups + TPB - 1) / TPB;
    aff_kernel<<<blocks, TPB, 0, stream>>>((const float4*)d_in[0], (const float4*)d_in[1],
                                           (const float4*)d_in[2], (const float4*)d_in[3],
                                           (float4*)d_out, B);
}

// Round 4
// 180.748 us; speedup vs baseline: 1.1204x; 1.1204x over previous
//
#include <hip/hip_runtime.h>
#include <math.h>

#define TPB 256
#define NT  4      // tiles (of 256 elements) per block

// R = I + a*K + b*K^2 with K=skew(v), K^2 = v v^T - th^2 I
// => R = (1 - b*th^2) I + b * v v^T + a * K   (matches reference incl. small-angle branch)
__device__ __forceinline__ void rodrigues(float v0, float v1, float v2, float R[9]) {
    float th2 = v0 * v0 + v1 * v1 + v2 * v2;
    float th  = sqrtf(th2);
    float s, c;
    sincosf(th, &s, &c);
    bool  sm = th < 1e-6f;
    float a  = sm ? 1.0f : s / th;
    float b  = sm ? 0.5f : (1.0f - c) / th2;
    float cc = 1.0f - b * th2;
    R[0] = cc + b * v0 * v0;      R[1] = b * v0 * v1 - a * v2;  R[2] = b * v0 * v2 + a * v1;
    R[3] = b * v0 * v1 + a * v2;  R[4] = cc + b * v1 * v1;      R[5] = b * v1 * v2 - a * v0;
    R[6] = b * v0 * v2 - a * v1;  R[7] = b * v1 * v2 + a * v0;  R[8] = cc + b * v2 * v2;
}

// Non-persistent: each block owns NT consecutive 256-element tiles.
// Per tile: LDS-staged coalesced float4 input AND output (round-0 pattern, exact
// WRITE_SIZE). Depth-1 register prefetch across the NT tiles hides global-load
// latency for tiles 1..NT-1 under the previous tile's compute+store.
__global__ __launch_bounds__(TPB) void aff_kernel(
    const float4* __restrict__ trans,
    const float4* __restrict__ rotat,
    const float4* __restrict__ sdir,
    const float4* __restrict__ scal,
    float4* __restrict__ out,
    int B, int T)
{
    __shared__ float4 s_in [TPB * 3];   // 12 KB flat: array a = float4s [a*192, (a+1)*192)
    __shared__ float4 s_out[TPB * 3];   // 12 KB: output slab (== global layout)

    const int tid = threadIdx.x;

    // Fixed per-thread mapping of 3 staged float4s onto the flat [768] tile slab:
    //   flat q0 = tid, q1 = tid+256, q2 = tid+512;  array = q/192, offset o = q%192.
    const float4* p0 = (tid < 192) ? (trans + tid)        : (rotat + (tid - 192));
    const float4* p1 = (tid < 128) ? (rotat + (tid + 64)) : (sdir  + (tid - 128));
    const float4* p2 = (tid < 64)  ? (sdir + (tid + 128)) : (scal  + (tid - 64));
    const int o0 = (tid < 192) ? tid       : tid - 192;
    const int o1 = (tid < 128) ? tid + 64  : tid - 128;
    const int o2 = (tid < 64)  ? tid + 128 : tid - 64;

    int tile = blockIdx.x * NT;
    if (tile >= T) return;                        // uniform across block
    const int tend = (tile + NT < T) ? tile + NT : T;

    float4 r0 = make_float4(0.f, 0.f, 0.f, 0.f);
    float4 r1 = r0, r2 = r0;

    {   // prime: prefetch first tile
        const int gb  = tile * (TPB * 3 / 4);     // 192 float4 per array per tile
        const int n   = min(TPB, B - tile * TPB);
        const int nq4 = (n * 3) >> 2;
        if (o0 < nq4) r0 = p0[gb];
        if (o1 < nq4) r1 = p1[gb];
        if (o2 < nq4) r2 = p2[gb];
    }

    for (; tile < tend; ++tile) {
        const int base = tile * TPB;
        const int n    = min(TPB, B - base);

        // staged regs -> LDS
        s_in[tid]       = r0;
        s_in[tid + 256] = r1;
        s_in[tid + 512] = r2;
        __syncthreads();

        // issue next tile's loads; latency hides under compute + store below
        if (tile + 1 < tend) {
            const int gb  = (tile + 1) * (TPB * 3 / 4);
            const int n2  = min(TPB, B - (tile + 1) * TPB);
            const int nq4 = (n2 * 3) >> 2;
            if (o0 < nq4) r0 = p0[gb];
            if (o1 < nq4) r1 = p1[gb];
            if (o2 < nq4) r2 = p2[gb];
        }

        if (tid < n) {
            const float* sf = (const float*)s_in;
            const float t0 = sf[3*tid+0], t1 = sf[3*tid+1], t2 = sf[3*tid+2];

            float R[9], U[9];
            rodrigues(sf[ 768+3*tid+0], sf[ 768+3*tid+1], sf[ 768+3*tid+2], R);
            rodrigues(sf[1536+3*tid+0], sf[1536+3*tid+1], sf[1536+3*tid+2], U);
            const float d0 = expf(sf[2304+3*tid+0]);
            const float d1 = expf(sf[2304+3*tid+1]);
            const float d2 = expf(sf[2304+3*tid+2]);

            // W = U * diag(d)
            const float W0 = U[0]*d0, W1 = U[1]*d1, W2 = U[2]*d2;
            const float W3 = U[3]*d0, W4 = U[4]*d1, W5 = U[5]*d2;
            const float W6 = U[6]*d0, W7 = U[7]*d1, W8 = U[8]*d2;

            // S = W * U^T (symmetric — verified passing in round 1)
            const float S00 = W0*U[0] + W1*U[1] + W2*U[2];
            const float S01 = W0*U[3] + W1*U[4] + W2*U[5];
            const float S02 = W0*U[6] + W1*U[7] + W2*U[8];
            const float S11 = W3*U[3] + W4*U[4] + W5*U[5];
            const float S12 = W3*U[6] + W4*U[7] + W5*U[8];
            const float S22 = W6*U[6] + W7*U[7] + W8*U[8];

            // M = R * S
            const float M00 = R[0]*S00 + R[1]*S01 + R[2]*S02;
            const float M01 = R[0]*S01 + R[1]*S11 + R[2]*S12;
            const float M02 = R[0]*S02 + R[1]*S12 + R[2]*S22;
            const float M10 = R[3]*S00 + R[4]*S01 + R[5]*S02;
            const float M11 = R[3]*S01 + R[4]*S11 + R[5]*S12;
            const float M12 = R[3]*S02 + R[4]*S12 + R[5]*S22;
            const float M20 = R[6]*S00 + R[7]*S01 + R[8]*S02;
            const float M21 = R[6]*S01 + R[7]*S11 + R[8]*S12;
            const float M22 = R[6]*S02 + R[7]*S12 + R[8]*S22;

            s_out[3*tid+0] = make_float4(M00, M01, M02, t0);
            s_out[3*tid+1] = make_float4(M10, M11, M12, t1);
            s_out[3*tid+2] = make_float4(M20, M21, M22, t2);
        }
        __syncthreads();

        // coalesced LDS -> global: up to 768 consecutive float4 per tile
        const int nq = n * 3;
        const int ob = base * 3;
#pragma unroll
        for (int p = 0; p < 3; ++p) {
            const int idx = p * TPB + tid;
            if (idx < nq) out[ob + idx] = s_out[idx];
        }
        // s_out LDS reads complete before each thread reaches the next iteration's
        // first barrier, so next iter's s_in/s_out writes are race-free.
    }
}

extern "C" void kernel_launch(void* const* d_in, const int* in_sizes, int n_in,
                              void* d_out, int out_size, void* d_ws, size_t ws_size,
                              hipStream_t stream) {
    int B = in_sizes[0] / 3;                     // 2,000,000 elements
    int T = (B + TPB - 1) / TPB;                 // 7813 tiles (last tile n=128)
    int blocks = (T + NT - 1) / NT;              // 1954 blocks, NT tiles each
    aff_kernel<<<blocks, TPB, 0, stream>>>((const float4*)d_in[0], (const float4*)d_in[1],
                                           (const float4*)d_in[2], (const float4*)d_in[3],
                                           (float4*)d_out, B, T);
}